// Round 2
// baseline (443.882 us; speedup 1.0000x reference)
//
#include <hip/hip_runtime.h>
#include <cstdint>
#include <cstddef>

#define B_ 4
#define T_ 2048
#define C_ 768
#define H_ 16
#define D_ 48
#define M_ (B_*T_)      // 8192
#define N3_ (3*C_)      // 2304

typedef unsigned short u16;
typedef __attribute__((ext_vector_type(8))) short bf16x8;
typedef __attribute__((ext_vector_type(4))) float f32x4;
typedef __attribute__((ext_vector_type(4))) unsigned int u32x4;
typedef __attribute__((ext_vector_type(4))) unsigned short u16x4;

typedef const __attribute__((address_space(1))) unsigned int* gptr_t;
typedef __attribute__((address_space(3))) unsigned int* lptr_t;

__device__ __forceinline__ u16 f2b(float f){
  union { float f; unsigned u; } x; x.f = f;
  unsigned u = x.u;
  return (u16)((u + 0x7FFFu + ((u >> 16) & 1u)) >> 16);
}

// Swizzled LDS fragment load. All LDS tiles use 128-byte row pitch.
// Physical byte = row*128 + (col_byte ^ ((row&7)<<4)).
__device__ __forceinline__ bf16x8 ld_frag(const u16* lds, int row, int kbyte){
  const char* p = (const char*)lds + (row << 7) + (kbyte ^ ((row & 7) << 4));
  return *(const bf16x8*)p;
}

// ---------------- fp32 -> bf16 convert (vectorized x4) ----------------
__global__ void k_cvt(const float* __restrict__ in, u16* __restrict__ out, int n4){
  int i = blockIdx.x * blockDim.x + threadIdx.x;
  if (i >= n4) return;
  f32x4 v = *(const f32x4*)(in + 4*(size_t)i);
  u16x4 o;
  o.x = f2b(v.x); o.y = f2b(v.y); o.z = f2b(v.z); o.w = f2b(v.w);
  *(u16x4*)(out + 4*(size_t)i) = o;
}

// ---------------- fp32 [R][Cn] -> bf16 transposed [Cn][R] ----------------
__global__ void k_tpose(const float* __restrict__ in, u16* __restrict__ out, int R, int Cn){
  __shared__ float tile[32][33];
  int tx = threadIdx.x & 31, ty = threadIdx.x >> 5;  // ty 0..7
  int c  = blockIdx.x * 32 + tx;
  int rb = blockIdx.y * 32;
  #pragma unroll
  for (int r0 = 0; r0 < 32; r0 += 8)
    tile[ty + r0][tx] = in[(size_t)(rb + ty + r0) * Cn + c];
  __syncthreads();
  int oc = rb + tx;
  int cb = blockIdx.x * 32;
  #pragma unroll
  for (int r0 = 0; r0 < 32; r0 += 8)
    out[(size_t)(cb + ty + r0) * R + oc] = f2b(tile[tx][ty + r0]);
}

// ---------------- bf16 GEMM: C[m][n] = sum_k A[m][k]*Bt[n][k] ----------------
// 128x128 tile, BK=64, 4 waves (2x2), each wave 4x4 frags of 16x16x32 MFMA.
// Staging via global_load_lds width=16: linear LDS dest, pre-swizzled source col.
template<bool OUT_BF16, bool ADD_BIAS>
__launch_bounds__(256)
__global__ void k_gemm(const u16* __restrict__ A, const u16* __restrict__ Bt,
                       void* __restrict__ Cout, const float* __restrict__ bias,
                       int Ndim, int Kdim){
  __shared__ u16 lA[128*64];
  __shared__ u16 lB[128*64];
  const int tid = threadIdx.x, lane = tid & 63, w = tid >> 6;
  const int m0 = blockIdx.x * 128, n0 = blockIdx.y * 128;
  const int wr = (w >> 1) * 64, wc = (w & 1) * 64;
  const f32x4 fzero = {0.f, 0.f, 0.f, 0.f};
  f32x4 acc[4][4];
  #pragma unroll
  for (int i = 0; i < 4; ++i)
    #pragma unroll
    for (int j = 0; j < 4; ++j) acc[i][j] = fzero;

  for (int k0 = 0; k0 < Kdim; k0 += 64){
    __syncthreads();
    #pragma unroll
    for (int it = 0; it < 4; ++it){
      int c = tid + it * 256;              // 0..1023
      int row  = c >> 3;
      int cb   = (c & 7) << 4;
      int pcol = cb ^ ((row & 7) << 4);
      const char* ga = (const char*)(A  + (size_t)(m0 + row) * Kdim + k0) + pcol;
      const char* gb = (const char*)(Bt + (size_t)(n0 + row) * Kdim + k0) + pcol;
      __builtin_amdgcn_global_load_lds((gptr_t)ga, (lptr_t)((char*)lA + (c << 4)), 16, 0, 0);
      __builtin_amdgcn_global_load_lds((gptr_t)gb, (lptr_t)((char*)lB + (c << 4)), 16, 0, 0);
    }
    __syncthreads();
    #pragma unroll
    for (int kk = 0; kk < 2; ++kk){
      int kbyte = (kk << 6) + ((lane >> 4) << 4);
      bf16x8 af[4], bfv[4];
      #pragma unroll
      for (int i = 0; i < 4; ++i){
        af[i]  = ld_frag(lA, wr + i*16 + (lane & 15), kbyte);
        bfv[i] = ld_frag(lB, wc + i*16 + (lane & 15), kbyte);
      }
      #pragma unroll
      for (int i = 0; i < 4; ++i)
        #pragma unroll
        for (int j = 0; j < 4; ++j)
          acc[i][j] = __builtin_amdgcn_mfma_f32_16x16x32_bf16(af[i], bfv[j], acc[i][j], 0, 0, 0);
    }
  }
  // epilogue: C row = (lane>>4)*4 + r, col = lane&15
  #pragma unroll
  for (int i = 0; i < 4; ++i){
    int rbase = m0 + wr + i*16 + ((lane >> 4) << 2);
    #pragma unroll
    for (int j = 0; j < 4; ++j){
      int col = n0 + wc + j*16 + (lane & 15);
      float bv = ADD_BIAS ? bias[col] : 0.f;
      #pragma unroll
      for (int r = 0; r < 4; ++r){
        float v = acc[i][j][r] + bv;
        if (OUT_BF16) ((u16*)Cout)[(size_t)(rbase + r) * Ndim + col] = f2b(v);
        else          ((float*)Cout)[(size_t)(rbase + r) * Ndim + col] = v;
      }
    }
  }
}

// ---------------- V transpose: vt[bh][d][t] from qkv ----------------
__global__ void k_vt(const u16* __restrict__ qkv, u16* __restrict__ vt){
  __shared__ u16 tl[64][50];
  int t0 = blockIdx.x * 64;
  int bh = blockIdx.y; int b = bh >> 4, h = bh & 15;
  int tid = threadIdx.x;
  for (int i = tid; i < 64*48; i += 256){
    int tt = i / 48, d = i % 48;
    tl[tt][d] = qkv[(size_t)(b*T_ + t0 + tt) * N3_ + 2*C_ + h*D_ + d];
  }
  __syncthreads();
  for (int i = tid; i < 48*64; i += 256){
    int d = i >> 6, tt = i & 63;
    vt[(size_t)(bh*D_ + d) * T_ + t0 + tt] = tl[tt][d];
  }
}

// ---------------- causal flash attention, barrier-free ----------------
// 1 wave per block (64 threads); wave owns 32 q rows. grid (T/32, B*H).
// Q/K/V fragments loaded directly from global (L1/L2-resident); only P
// round-trips through a private 4KB swizzled LDS tile. No __syncthreads.
__launch_bounds__(64, 4)
__global__ void k_attn(const u16* __restrict__ qkv, const u16* __restrict__ vt,
                       u16* __restrict__ ao){
  __shared__ u16 lP[32*64];            // 32 rows x 128B, swizzled
  const int qt = blockIdx.x * 32;      // first q row of this wave
  const int bh = blockIdx.y;
  const int b = bh >> 4, h = bh & 15;
  const int lane = threadIdx.x & 63;
  const int ls = lane & 15, hi = lane >> 4;
  const f32x4 fzero = {0.f, 0.f, 0.f, 0.f};
  const bf16x8 bzero = {0, 0, 0, 0, 0, 0, 0, 0};
  const float scale2 = 0.20823527f;    // 48^-0.5 * log2(e)

  // Q fragments direct from global: A[q][k], q = qt+af*16+ls, k = hi*8 + kk*32
  bf16x8 aq[2][2];
  #pragma unroll
  for (int af = 0; af < 2; ++af){
    const u16* qp = qkv + (size_t)(b*T_ + qt + af*16 + ls) * N3_ + h*D_ + hi*8;
    aq[af][0] = *(const bf16x8*)qp;
    aq[af][1] = (hi < 2) ? *(const bf16x8*)(qp + 32) : bzero;
  }

  const u16* kbase = qkv + (size_t)b*T_*N3_ + C_ + h*D_ + hi*8;  // + row*N3_ + kk*32
  const u16* vbase = vt + (size_t)bh*D_*T_ + hi*8;               // + d*T_ + kb*64 + kk*32

  float mrun[8], lsum[8];
  f32x4 oacc[2][3];
  #pragma unroll
  for (int i = 0; i < 8; ++i){ mrun[i] = -1e30f; lsum[i] = 0.f; }
  #pragma unroll
  for (int af = 0; af < 2; ++af)
    #pragma unroll
    for (int nf = 0; nf < 3; ++nf) oacc[af][nf] = fzero;

  const int kbmax = (qt + 31) >> 6;
  for (int kb = 0; kb <= kbmax; ++kb){
    const int krow0 = kb * 64;
    // ---- S = Q K^T ----
    f32x4 s[2][4];
    #pragma unroll
    for (int af = 0; af < 2; ++af)
      #pragma unroll
      for (int nf = 0; nf < 4; ++nf) s[af][nf] = fzero;
    #pragma unroll
    for (int kk = 0; kk < 2; ++kk){
      bf16x8 bk[4];
      #pragma unroll
      for (int nf = 0; nf < 4; ++nf){
        const u16* kp = kbase + (size_t)(krow0 + nf*16 + ls) * N3_ + kk*32;
        bk[nf] = (kk == 1 && hi >= 2) ? bzero : *(const bf16x8*)kp;
      }
      #pragma unroll
      for (int nf = 0; nf < 4; ++nf){
        s[0][nf] = __builtin_amdgcn_mfma_f32_16x16x32_bf16(aq[0][kk], bk[nf], s[0][nf], 0, 0, 0);
        s[1][nf] = __builtin_amdgcn_mfma_f32_16x16x32_bf16(aq[1][kk], bk[nf], s[1][nf], 0, 0, 0);
      }
    }
    // ---- scale (+ causal mask only on the diagonal tile) ----
    #pragma unroll
    for (int af = 0; af < 2; ++af)
      #pragma unroll
      for (int nf = 0; nf < 4; ++nf)
        #pragma unroll
        for (int r = 0; r < 4; ++r)
          s[af][nf][r] *= scale2;
    if (kb == kbmax){
      #pragma unroll
      for (int af = 0; af < 2; ++af)
        #pragma unroll
        for (int r = 0; r < 4; ++r){
          int qg = qt + af*16 + hi*4 + r;
          #pragma unroll
          for (int nf = 0; nf < 4; ++nf){
            int kg = krow0 + nf*16 + ls;
            s[af][nf][r] = (kg <= qg) ? s[af][nf][r] : -1e30f;
          }
        }
    }
    // ---- row max: in-lane over nf, then xor-reduce over the 16-lane group ----
    float rmax[8];
    #pragma unroll
    for (int af = 0; af < 2; ++af)
      #pragma unroll
      for (int r = 0; r < 4; ++r)
        rmax[af*4+r] = fmaxf(fmaxf(s[af][0][r], s[af][1][r]),
                             fmaxf(s[af][2][r], s[af][3][r]));
    #pragma unroll
    for (int off = 8; off; off >>= 1)
      #pragma unroll
      for (int i = 0; i < 8; ++i)
        rmax[i] = fmaxf(rmax[i], __shfl_xor(rmax[i], off));
    // ---- rescale running state ----
    float corr[8];
    #pragma unroll
    for (int i = 0; i < 8; ++i){
      float mn = fmaxf(mrun[i], rmax[i]);
      corr[i] = __builtin_amdgcn_exp2f(mrun[i] - mn);
      mrun[i] = mn;
      lsum[i] *= corr[i];
    }
    #pragma unroll
    for (int af = 0; af < 2; ++af)
      #pragma unroll
      for (int nf = 0; nf < 3; ++nf)
        #pragma unroll
        for (int r = 0; r < 4; ++r)
          oacc[af][nf][r] *= corr[af*4+r];
    // ---- exp; per-lane partial row sums (full reduce deferred to epilogue) ----
    #pragma unroll
    for (int af = 0; af < 2; ++af)
      #pragma unroll
      for (int nf = 0; nf < 4; ++nf)
        #pragma unroll
        for (int r = 0; r < 4; ++r){
          float e = __builtin_amdgcn_exp2f(s[af][nf][r] - mrun[af*4+r]);
          s[af][nf][r] = e;
          lsum[af*4+r] += e;
        }
    // ---- V fragments (issued before P write for latency cover) ----
    bf16x8 bv[3][2];
    #pragma unroll
    for (int nf = 0; nf < 3; ++nf){
      const u16* vp = vbase + (size_t)(nf*16 + ls) * T_ + krow0;
      bv[nf][0] = *(const bf16x8*)vp;
      bv[nf][1] = *(const bf16x8*)(vp + 32);
    }
    // ---- P -> LDS (bf16, swizzled) ----
    #pragma unroll
    for (int af = 0; af < 2; ++af)
      #pragma unroll
      for (int r = 0; r < 4; ++r){
        int prow = af*16 + hi*4 + r;
        int sw = (prow & 7) << 4;
        char* rowp = (char*)lP + (prow << 7);
        #pragma unroll
        for (int nf = 0; nf < 4; ++nf){
          int cb = ((nf*16 + ls) << 1) ^ sw;
          *(u16*)(rowp + cb) = f2b(s[af][nf][r]);
        }
      }
    // ---- O += P V ----
    #pragma unroll
    for (int kk = 0; kk < 2; ++kk){
      int kbyte = (kk << 6) + (hi << 4);
      #pragma unroll
      for (int af = 0; af < 2; ++af){
        bf16x8 pa = ld_frag(lP, af*16 + ls, kbyte);
        #pragma unroll
        for (int nf = 0; nf < 3; ++nf)
          oacc[af][nf] = __builtin_amdgcn_mfma_f32_16x16x32_bf16(pa, bv[nf][kk], oacc[af][nf], 0, 0, 0);
      }
    }
  }

  // ---- epilogue: finish the deferred sum reduce, normalize, store ----
  #pragma unroll
  for (int off = 8; off; off >>= 1)
    #pragma unroll
    for (int i = 0; i < 8; ++i)
      lsum[i] += __shfl_xor(lsum[i], off);
  #pragma unroll
  for (int af = 0; af < 2; ++af)
    #pragma unroll
    for (int r = 0; r < 4; ++r){
      float inv = 1.f / lsum[af*4+r];
      int t = qt + af*16 + hi*4 + r;
      #pragma unroll
      for (int nf = 0; nf < 3; ++nf){
        int col = h*D_ + nf*16 + ls;
        ao[(size_t)(b*T_ + t) * C_ + col] = f2b(oacc[af][nf][r] * inv);
      }
    }
}

extern "C" void kernel_launch(void* const* d_in, const int* in_sizes, int n_in,
                              void* d_out, int out_size, void* d_ws, size_t ws_size,
                              hipStream_t stream){
  if (n_in < 4) return;
  const float* x      = (const float*)d_in[0];
  const float* W_attn = (const float*)d_in[1];
  const float* W_proj = (const float*)d_in[2];
  const float* b_proj = (const float*)d_in[3];

  char* ws = (char*)d_ws;
  size_t off = 0;
  auto alloc = [&](size_t bytes)->void*{
    void* p = ws + off; off += (bytes + 255) & ~(size_t)255; return p;
  };
  u16* xb   = (u16*)alloc((size_t)M_ * C_  * 2);
  u16* wabT = (u16*)alloc((size_t)N3_ * C_ * 2);
  u16* wpbT = (u16*)alloc((size_t)C_ * C_  * 2);
  u16* qkv  = (u16*)alloc((size_t)M_ * N3_ * 2);
  u16* vt   = (u16*)alloc((size_t)B_ * H_ * D_ * T_ * 2);
  u16* ao   = (u16*)alloc((size_t)M_ * C_  * 2);
  if (off > ws_size) return;  // workspace too small — bail cleanly

  k_cvt<<<dim3((M_*C_/4 + 255)/256), dim3(256), 0, stream>>>(x, xb, M_*C_/4);
  k_tpose<<<dim3(N3_/32, C_/32), dim3(256), 0, stream>>>(W_attn, wabT, C_, N3_);
  k_tpose<<<dim3(C_/32,  C_/32), dim3(256), 0, stream>>>(W_proj, wpbT, C_, C_);
  k_gemm<true,false><<<dim3(M_/128, N3_/128), dim3(256), 0, stream>>>(
      xb, wabT, (void*)qkv, (const float*)nullptr, N3_, C_);
  k_vt<<<dim3(T_/64, B_*H_), dim3(256), 0, stream>>>(qkv, vt);
  k_attn<<<dim3(T_/32, B_*H_), dim3(64), 0, stream>>>(qkv, vt, ao);
  k_gemm<false,true><<<dim3(M_/128, C_/128), dim3(256), 0, stream>>>(
      ao, wpbT, d_out, b_proj, C_, C_);
}

// Round 5
// 196.955 us; speedup vs baseline: 2.2537x; 2.2537x over previous
//
#include <hip/hip_runtime.h>
#include <cstdint>
#include <cstddef>

#define B_ 4
#define T_ 2048
#define C_ 768
#define H_ 16
#define D_ 48
#define M_ (B_*T_)      // 8192
#define N3_ (3*C_)      // 2304

typedef unsigned short u16;
typedef __attribute__((ext_vector_type(8))) short bf16x8;
typedef __attribute__((ext_vector_type(4))) float f32x4;
typedef __attribute__((ext_vector_type(4))) unsigned int u32x4;
typedef __attribute__((ext_vector_type(4))) unsigned short u16x4;

typedef const __attribute__((address_space(1))) unsigned int* gptr_t;
typedef __attribute__((address_space(3))) unsigned int* lptr_t;

__device__ __forceinline__ u16 f2b(float f){
  union { float f; unsigned u; } x; x.f = f;
  unsigned u = x.u;
  return (u16)((u + 0x7FFFu + ((u >> 16) & 1u)) >> 16);
}

// Swizzled LDS fragment load. All LDS tiles use 128-byte row pitch.
// Physical byte = row*128 + (col_byte ^ ((row&7)<<4)).
__device__ __forceinline__ bf16x8 ld_frag(const u16* lds, int row, int kbyte){
  const char* p = (const char*)lds + (row << 7) + (kbyte ^ ((row & 7) << 4));
  return *(const bf16x8*)p;
}

// ---------------- fp32 -> bf16 convert (vectorized x4) ----------------
__global__ void k_cvt(const float* __restrict__ in, u16* __restrict__ out, int n4){
  int i = blockIdx.x * blockDim.x + threadIdx.x;
  if (i >= n4) return;
  f32x4 v = *(const f32x4*)(in + 4*(size_t)i);
  u16x4 o;
  o.x = f2b(v.x); o.y = f2b(v.y); o.z = f2b(v.z); o.w = f2b(v.w);
  *(u16x4*)(out + 4*(size_t)i) = o;
}

// ---------------- fp32 [R][Cn] -> bf16 transposed [Cn][R] ----------------
__global__ void k_tpose(const float* __restrict__ in, u16* __restrict__ out, int R, int Cn){
  __shared__ float tile[32][33];
  int tx = threadIdx.x & 31, ty = threadIdx.x >> 5;  // ty 0..7
  int c  = blockIdx.x * 32 + tx;
  int rb = blockIdx.y * 32;
  #pragma unroll
  for (int r0 = 0; r0 < 32; r0 += 8)
    tile[ty + r0][tx] = in[(size_t)(rb + ty + r0) * Cn + c];
  __syncthreads();
  int oc = rb + tx;
  int cb = blockIdx.x * 32;
  #pragma unroll
  for (int r0 = 0; r0 < 32; r0 += 8)
    out[(size_t)(cb + ty + r0) * R + oc] = f2b(tile[tx][ty + r0]);
}

// ---------------- bf16 GEMM: C[m][n] = sum_k A[m][k]*Bt[n][k] ----------------
// 128x128 tile, BK=64, 4 waves (2x2), each wave 4x4 frags of 16x16x32 MFMA.
// Staging via global_load_lds width=16: linear LDS dest, pre-swizzled source col.
template<bool OUT_BF16, bool ADD_BIAS>
__launch_bounds__(256)
__global__ void k_gemm(const u16* __restrict__ A, const u16* __restrict__ Bt,
                       void* __restrict__ Cout, const float* __restrict__ bias,
                       int Ndim, int Kdim){
  __shared__ u16 lA[128*64];
  __shared__ u16 lB[128*64];
  const int tid = threadIdx.x, lane = tid & 63, w = tid >> 6;
  const int m0 = blockIdx.x * 128, n0 = blockIdx.y * 128;
  const int wr = (w >> 1) * 64, wc = (w & 1) * 64;
  const f32x4 fzero = {0.f, 0.f, 0.f, 0.f};
  f32x4 acc[4][4];
  #pragma unroll
  for (int i = 0; i < 4; ++i)
    #pragma unroll
    for (int j = 0; j < 4; ++j) acc[i][j] = fzero;

  for (int k0 = 0; k0 < Kdim; k0 += 64){
    __syncthreads();
    #pragma unroll
    for (int it = 0; it < 4; ++it){
      int c = tid + it * 256;              // 0..1023
      int row  = c >> 3;
      int cb   = (c & 7) << 4;
      int pcol = cb ^ ((row & 7) << 4);
      const char* ga = (const char*)(A  + (size_t)(m0 + row) * Kdim + k0) + pcol;
      const char* gb = (const char*)(Bt + (size_t)(n0 + row) * Kdim + k0) + pcol;
      __builtin_amdgcn_global_load_lds((gptr_t)ga, (lptr_t)((char*)lA + (c << 4)), 16, 0, 0);
      __builtin_amdgcn_global_load_lds((gptr_t)gb, (lptr_t)((char*)lB + (c << 4)), 16, 0, 0);
    }
    __syncthreads();
    #pragma unroll
    for (int kk = 0; kk < 2; ++kk){
      int kbyte = (kk << 6) + ((lane >> 4) << 4);
      bf16x8 af[4], bfv[4];
      #pragma unroll
      for (int i = 0; i < 4; ++i){
        af[i]  = ld_frag(lA, wr + i*16 + (lane & 15), kbyte);
        bfv[i] = ld_frag(lB, wc + i*16 + (lane & 15), kbyte);
      }
      #pragma unroll
      for (int i = 0; i < 4; ++i)
        #pragma unroll
        for (int j = 0; j < 4; ++j)
          acc[i][j] = __builtin_amdgcn_mfma_f32_16x16x32_bf16(af[i], bfv[j], acc[i][j], 0, 0, 0);
    }
  }
  // epilogue: C row = (lane>>4)*4 + r, col = lane&15
  #pragma unroll
  for (int i = 0; i < 4; ++i){
    int rbase = m0 + wr + i*16 + ((lane >> 4) << 2);
    #pragma unroll
    for (int j = 0; j < 4; ++j){
      int col = n0 + wc + j*16 + (lane & 15);
      float bv = ADD_BIAS ? bias[col] : 0.f;
      #pragma unroll
      for (int r = 0; r < 4; ++r){
        float v = acc[i][j][r] + bv;
        if (OUT_BF16) ((u16*)Cout)[(size_t)(rbase + r) * Ndim + col] = f2b(v);
        else          ((float*)Cout)[(size_t)(rbase + r) * Ndim + col] = v;
      }
    }
  }
}

// ---------------- V transpose: vt[bh][d][t] from qkv ----------------
__global__ void k_vt(const u16* __restrict__ qkv, u16* __restrict__ vt){
  __shared__ u16 tl[64][50];
  int t0 = blockIdx.x * 64;
  int bh = blockIdx.y; int b = bh >> 4, h = bh & 15;
  int tid = threadIdx.x;
  for (int i = tid; i < 64*48; i += 256){
    int tt = i / 48, d = i % 48;
    tl[tt][d] = qkv[(size_t)(b*T_ + t0 + tt) * N3_ + 2*C_ + h*D_ + d];
  }
  __syncthreads();
  for (int i = tid; i < 48*64; i += 256){
    int d = i >> 6, tt = i & 63;
    vt[(size_t)(bh*D_ + d) * T_ + t0 + tt] = tl[tt][d];
  }
}

// ---------------- causal flash attention, double-buffered 2-phase ----------------
// grid: 1D 2048 blocks (XCD-swizzled); block = 256 (4 waves); wave w owns q rows
// [qb*64 + w*16, +16). K/V tiles of 64 keys double-buffered in LDS via
// global_load_lds (linear dest, inverse-swizzled source). One barrier per tile.
__launch_bounds__(256)
__global__ void k_attn(const u16* __restrict__ qkv, const u16* __restrict__ vt,
                       u16* __restrict__ ao){
  __shared__ u16 lK[2][64*64];   // 64 rows x 128B (96B valid + 32B garbage pad)
  __shared__ u16 lV[2][48*64];   // 48 d-rows x 128B (64 keys)
  __shared__ u16 lP[4][16*64];   // per-wave 16 rows x 128B, swizzled

  // XCD swizzle: 2048 blocks, 8 XCDs, 256 per XCD; each XCD gets 8 full bh groups.
  const int wg = ((blockIdx.x & 7) << 8) + (blockIdx.x >> 3);
  const int qb = wg & 31, bh = wg >> 5;
  const int b = bh >> 4, h = bh & 15;
  const int tid = threadIdx.x, lane = tid & 63, w = tid >> 6;
  const int ls = lane & 15, hi = lane >> 4;
  const f32x4 fzero = {0.f, 0.f, 0.f, 0.f};
  const bf16x8 bzero = {0, 0, 0, 0, 0, 0, 0, 0};
  const float scale2 = 0.20823527f;    // 48^-0.5 * log2(e)

  // ---- Q fragments direct from global (one-time) ----
  bf16x8 aq[2];
  {
    const u16* qp = qkv + (size_t)(b*T_ + qb*64 + w*16 + ls) * N3_ + h*D_ + hi*8;
    aq[0] = *(const bf16x8*)qp;
    aq[1] = (hi < 2) ? *(const bf16x8*)(qp + 32) : bzero;   // k in [48,64) zeroed
  }

  // ---- staging: precompute per-thread source offsets ----
  // chunk c -> LDS linear byte c*16; logical row = c>>3, logical col byte
  // cbl = ((c&7)<<4) ^ ((row&7)<<4)  (inverse swizzle on the source side).
  const char* kg0; const char* kg1; const char* vg0; const char* vg1;
  {
    int c0 = tid,        r0 = c0 >> 3, cb0 = ((c0 & 7) << 4) ^ ((r0 & 7) << 4);
    int c1 = tid + 256,  r1 = c1 >> 3, cb1 = ((c1 & 7) << 4) ^ ((r1 & 7) << 4);
    kg0 = (const char*)(qkv + (size_t)(b*T_ + r0) * N3_ + C_ + h*D_) + cb0;
    kg1 = (const char*)(qkv + (size_t)(b*T_ + r1) * N3_ + C_ + h*D_) + cb1;
    vg0 = (const char*)(vt + (size_t)(bh*D_ + r0) * T_) + cb0;
    vg1 = (const char*)(vt + (size_t)(bh*D_ + (tid < 128 ? r1 : 0)) * T_) + cb1;
  }
  const size_t kstep = (size_t)64 * N3_ * 2;   // advance 64 K-rows per tile
  const size_t vstep = (size_t)64 * 2;         // advance 64 keys per tile

  auto STAGE = [&](int kb, int buf){
    const size_t ko = (size_t)kb * kstep, vo = (size_t)kb * vstep;
    __builtin_amdgcn_global_load_lds((gptr_t)(kg0 + ko),
        (lptr_t)((char*)lK[buf] + (tid << 4)), 16, 0, 0);
    __builtin_amdgcn_global_load_lds((gptr_t)(kg1 + ko),
        (lptr_t)((char*)lK[buf] + ((tid + 256) << 4)), 16, 0, 0);
    __builtin_amdgcn_global_load_lds((gptr_t)(vg0 + vo),
        (lptr_t)((char*)lV[buf] + (tid << 4)), 16, 0, 0);
    if (tid < 128)
      __builtin_amdgcn_global_load_lds((gptr_t)(vg1 + vo),
          (lptr_t)((char*)lV[buf] + ((tid + 256) << 4)), 16, 0, 0);
  };

  float mrun[4], lsum[4];
  f32x4 oacc[3];
  #pragma unroll
  for (int i = 0; i < 4; ++i){ mrun[i] = -1e30f; lsum[i] = 0.f; }
  #pragma unroll
  for (int nf = 0; nf < 3; ++nf) oacc[nf] = fzero;

  const int kbmax = qb;
  STAGE(0, 0);
  __syncthreads();       // implicit vmcnt(0) drain
  int cur = 0;

  for (int kb = 0; kb <= kbmax; ++kb){
    if (kb < kbmax) STAGE(kb + 1, cur ^ 1);   // prefetch next tile

    // ---- S = Q K^T ----
    f32x4 s[4];
    #pragma unroll
    for (int nf = 0; nf < 4; ++nf) s[nf] = fzero;
    #pragma unroll
    for (int kk = 0; kk < 2; ++kk){
      int kbyte = (kk << 6) + (hi << 4);
      #pragma unroll
      for (int nf = 0; nf < 4; ++nf){
        bf16x8 bk = ld_frag(lK[cur], nf*16 + ls, kbyte);
        s[nf] = __builtin_amdgcn_mfma_f32_16x16x32_bf16(aq[kk], bk, s[nf], 0, 0, 0);
      }
    }

    // ---- scale (+ causal mask on diagonal tile only) ----
    #pragma unroll
    for (int nf = 0; nf < 4; ++nf)
      #pragma unroll
      for (int r = 0; r < 4; ++r)
        s[nf][r] *= scale2;
    if (kb == kbmax){
      #pragma unroll
      for (int r = 0; r < 4; ++r){
        int qg = qb*64 + w*16 + hi*4 + r;
        #pragma unroll
        for (int nf = 0; nf < 4; ++nf){
          int kg = kb*64 + nf*16 + ls;
          s[nf][r] = (kg <= qg) ? s[nf][r] : -1e30f;
        }
      }
    }

    // ---- row max: in-lane over nf, xor-reduce over 16-lane key group ----
    float rmax[4];
    #pragma unroll
    for (int r = 0; r < 4; ++r)
      rmax[r] = fmaxf(fmaxf(s[0][r], s[1][r]), fmaxf(s[2][r], s[3][r]));
    #pragma unroll
    for (int off = 8; off; off >>= 1)
      #pragma unroll
      for (int r = 0; r < 4; ++r)
        rmax[r] = fmaxf(rmax[r], __shfl_xor(rmax[r], off));

    // ---- rescale running state ----
    float corr[4];
    #pragma unroll
    for (int r = 0; r < 4; ++r){
      float mn = fmaxf(mrun[r], rmax[r]);
      corr[r] = __builtin_amdgcn_exp2f(mrun[r] - mn);
      mrun[r] = mn;
      lsum[r] *= corr[r];
    }
    #pragma unroll
    for (int nf = 0; nf < 3; ++nf)
      #pragma unroll
      for (int r = 0; r < 4; ++r)
        oacc[nf][r] *= corr[r];

    // ---- exp; per-lane partial sums (full reduce deferred to epilogue) ----
    #pragma unroll
    for (int nf = 0; nf < 4; ++nf)
      #pragma unroll
      for (int r = 0; r < 4; ++r){
        float e = __builtin_amdgcn_exp2f(s[nf][r] - mrun[r]);
        s[nf][r] = e;
        lsum[r] += e;
      }

    // ---- P -> per-wave swizzled LDS tile ----
    u16* myP = &lP[w][0];
    #pragma unroll
    for (int r = 0; r < 4; ++r){
      int prow = hi*4 + r;
      int sw = (prow & 7) << 4;
      char* rowp = (char*)myP + (prow << 7);
      #pragma unroll
      for (int nf = 0; nf < 4; ++nf)
        *(u16*)(rowp + (((nf*16 + ls) << 1) ^ sw)) = f2b(s[nf][r]);
    }

    // ---- O += P V ----
    #pragma unroll
    for (int kk = 0; kk < 2; ++kk){
      int kbyte = (kk << 6) + (hi << 4);
      bf16x8 pa = ld_frag(myP, ls, kbyte);
      #pragma unroll
      for (int nf = 0; nf < 3; ++nf){
        bf16x8 bv = ld_frag(lV[cur], nf*16 + ls, kbyte);
        oacc[nf] = __builtin_amdgcn_mfma_f32_16x16x32_bf16(pa, bv, oacc[nf], 0, 0, 0);
      }
    }

    if (kb < kbmax){
      __syncthreads();   // implicit vmcnt(0): prefetched tile is now resident
      cur ^= 1;
    }
  }

  // ---- epilogue: finish deferred sum reduce, normalize, store ----
  #pragma unroll
  for (int off = 8; off; off >>= 1)
    #pragma unroll
    for (int r = 0; r < 4; ++r)
      lsum[r] += __shfl_xor(lsum[r], off);
  #pragma unroll
  for (int r = 0; r < 4; ++r){
    float inv = 1.f / lsum[r];
    int t = qb*64 + w*16 + hi*4 + r;
    #pragma unroll
    for (int nf = 0; nf < 3; ++nf){
      int col = h*D_ + nf*16 + ls;
      ao[(size_t)(b*T_ + t) * C_ + col] = f2b(oacc[nf][r] * inv);
    }
  }
}

extern "C" void kernel_launch(void* const* d_in, const int* in_sizes, int n_in,
                              void* d_out, int out_size, void* d_ws, size_t ws_size,
                              hipStream_t stream){
  if (n_in < 4) return;
  const float* x      = (const float*)d_in[0];
  const float* W_attn = (const float*)d_in[1];
  const float* W_proj = (const float*)d_in[2];
  const float* b_proj = (const float*)d_in[3];

  char* ws = (char*)d_ws;
  size_t off = 0;
  auto alloc = [&](size_t bytes)->void*{
    void* p = ws + off; off += (bytes + 255) & ~(size_t)255; return p;
  };
  u16* xb   = (u16*)alloc((size_t)M_ * C_  * 2);
  u16* wabT = (u16*)alloc((size_t)N3_ * C_ * 2);
  u16* wpbT = (u16*)alloc((size_t)C_ * C_  * 2);
  u16* qkv  = (u16*)alloc((size_t)M_ * N3_ * 2);
  u16* vt   = (u16*)alloc((size_t)B_ * H_ * D_ * T_ * 2);
  u16* ao   = (u16*)alloc((size_t)M_ * C_  * 2);
  if (off > ws_size) return;  // workspace too small — bail cleanly

  k_cvt<<<dim3((M_*C_/4 + 255)/256), dim3(256), 0, stream>>>(x, xb, M_*C_/4);
  k_tpose<<<dim3(N3_/32, C_/32), dim3(256), 0, stream>>>(W_attn, wabT, C_, N3_);
  k_tpose<<<dim3(C_/32,  C_/32), dim3(256), 0, stream>>>(W_proj, wpbT, C_, C_);
  k_gemm<true,false><<<dim3(M_/128, N3_/128), dim3(256), 0, stream>>>(
      xb, wabT, (void*)qkv, (const float*)nullptr, N3_, C_);
  k_vt<<<dim3(T_/64, B_*H_), dim3(256), 0, stream>>>(qkv, vt);
  k_attn<<<dim3(2048), dim3(256), 0, stream>>>(qkv, vt, ao);
  k_gemm<false,true><<<dim3(M_/128, C_/128), dim3(256), 0, stream>>>(
      ao, wpbT, d_out, b_proj, C_, C_);
}

// Round 6
// 193.231 us; speedup vs baseline: 2.2972x; 1.0193x over previous
//
#include <hip/hip_runtime.h>
#include <cstdint>
#include <cstddef>

#define B_ 4
#define T_ 2048
#define C_ 768
#define H_ 16
#define D_ 48
#define M_ (B_*T_)      // 8192
#define N3_ (3*C_)      // 2304

typedef unsigned short u16;
typedef __attribute__((ext_vector_type(8))) short bf16x8;
typedef __attribute__((ext_vector_type(4))) float f32x4;
typedef __attribute__((ext_vector_type(4))) unsigned int u32x4;
typedef __attribute__((ext_vector_type(4))) unsigned short u16x4;

typedef const __attribute__((address_space(1))) unsigned int* gptr_t;
typedef __attribute__((address_space(3))) unsigned int* lptr_t;

__device__ __forceinline__ u16 f2b(float f){
  union { float f; unsigned u; } x; x.f = f;
  unsigned u = x.u;
  return (u16)((u + 0x7FFFu + ((u >> 16) & 1u)) >> 16);
}

// Swizzled LDS fragment load. All LDS tiles use 128-byte row pitch.
// Physical byte = row*128 + (col_byte ^ ((row&7)<<4)).
__device__ __forceinline__ bf16x8 ld_frag(const u16* lds, int row, int kbyte){
  const char* p = (const char*)lds + (row << 7) + (kbyte ^ ((row & 7) << 4));
  return *(const bf16x8*)p;
}

// ---- DPP 16-lane row reduce (VALU pipe, no LDS traffic) ----
template<int N>
__device__ __forceinline__ float dpp_ror(float v){
  int r = __builtin_amdgcn_update_dpp(__float_as_int(v), __float_as_int(v),
                                      0x120 | N, 0xF, 0xF, false);
  return __int_as_float(r);
}
__device__ __forceinline__ float rowmax16(float x){
  x = fmaxf(x, dpp_ror<1>(x));
  x = fmaxf(x, dpp_ror<2>(x));
  x = fmaxf(x, dpp_ror<4>(x));
  x = fmaxf(x, dpp_ror<8>(x));
  return x;
}
__device__ __forceinline__ float rowsum16(float x){
  x = x + dpp_ror<1>(x);
  x = x + dpp_ror<2>(x);
  x = x + dpp_ror<4>(x);
  x = x + dpp_ror<8>(x);
  return x;
}

// ---------------- fp32 -> bf16 convert (vectorized x4) ----------------
__global__ void k_cvt(const float* __restrict__ in, u16* __restrict__ out, int n4){
  int i = blockIdx.x * blockDim.x + threadIdx.x;
  if (i >= n4) return;
  f32x4 v = *(const f32x4*)(in + 4*(size_t)i);
  u16x4 o;
  o.x = f2b(v.x); o.y = f2b(v.y); o.z = f2b(v.z); o.w = f2b(v.w);
  *(u16x4*)(out + 4*(size_t)i) = o;
}

// ---------------- fp32 [R][Cn] -> bf16 transposed [Cn][R] ----------------
__global__ void k_tpose(const float* __restrict__ in, u16* __restrict__ out, int R, int Cn){
  __shared__ float tile[32][33];
  int tx = threadIdx.x & 31, ty = threadIdx.x >> 5;  // ty 0..7
  int c  = blockIdx.x * 32 + tx;
  int rb = blockIdx.y * 32;
  #pragma unroll
  for (int r0 = 0; r0 < 32; r0 += 8)
    tile[ty + r0][tx] = in[(size_t)(rb + ty + r0) * Cn + c];
  __syncthreads();
  int oc = rb + tx;
  int cb = blockIdx.x * 32;
  #pragma unroll
  for (int r0 = 0; r0 < 32; r0 += 8)
    out[(size_t)(cb + ty + r0) * R + oc] = f2b(tile[tx][ty + r0]);
}

// ---------------- bf16 GEMM: C[m][n] = sum_k A[m][k]*Bt[n][k] ----------------
template<bool OUT_BF16, bool ADD_BIAS>
__launch_bounds__(256)
__global__ void k_gemm(const u16* __restrict__ A, const u16* __restrict__ Bt,
                       void* __restrict__ Cout, const float* __restrict__ bias,
                       int Ndim, int Kdim){
  __shared__ u16 lA[128*64];
  __shared__ u16 lB[128*64];
  const int tid = threadIdx.x, lane = tid & 63, w = tid >> 6;
  const int m0 = blockIdx.x * 128, n0 = blockIdx.y * 128;
  const int wr = (w >> 1) * 64, wc = (w & 1) * 64;
  const f32x4 fzero = {0.f, 0.f, 0.f, 0.f};
  f32x4 acc[4][4];
  #pragma unroll
  for (int i = 0; i < 4; ++i)
    #pragma unroll
    for (int j = 0; j < 4; ++j) acc[i][j] = fzero;

  for (int k0 = 0; k0 < Kdim; k0 += 64){
    __syncthreads();
    #pragma unroll
    for (int it = 0; it < 4; ++it){
      int c = tid + it * 256;              // 0..1023
      int row  = c >> 3;
      int cb   = (c & 7) << 4;
      int pcol = cb ^ ((row & 7) << 4);
      const char* ga = (const char*)(A  + (size_t)(m0 + row) * Kdim + k0) + pcol;
      const char* gb = (const char*)(Bt + (size_t)(n0 + row) * Kdim + k0) + pcol;
      __builtin_amdgcn_global_load_lds((gptr_t)ga, (lptr_t)((char*)lA + (c << 4)), 16, 0, 0);
      __builtin_amdgcn_global_load_lds((gptr_t)gb, (lptr_t)((char*)lB + (c << 4)), 16, 0, 0);
    }
    __syncthreads();
    #pragma unroll
    for (int kk = 0; kk < 2; ++kk){
      int kbyte = (kk << 6) + ((lane >> 4) << 4);
      bf16x8 af[4], bfv[4];
      #pragma unroll
      for (int i = 0; i < 4; ++i){
        af[i]  = ld_frag(lA, wr + i*16 + (lane & 15), kbyte);
        bfv[i] = ld_frag(lB, wc + i*16 + (lane & 15), kbyte);
      }
      #pragma unroll
      for (int i = 0; i < 4; ++i)
        #pragma unroll
        for (int j = 0; j < 4; ++j)
          acc[i][j] = __builtin_amdgcn_mfma_f32_16x16x32_bf16(af[i], bfv[j], acc[i][j], 0, 0, 0);
    }
  }
  #pragma unroll
  for (int i = 0; i < 4; ++i){
    int rbase = m0 + wr + i*16 + ((lane >> 4) << 2);
    #pragma unroll
    for (int j = 0; j < 4; ++j){
      int col = n0 + wc + j*16 + (lane & 15);
      float bv = ADD_BIAS ? bias[col] : 0.f;
      #pragma unroll
      for (int r = 0; r < 4; ++r){
        float v = acc[i][j][r] + bv;
        if (OUT_BF16) ((u16*)Cout)[(size_t)(rbase + r) * Ndim + col] = f2b(v);
        else          ((float*)Cout)[(size_t)(rbase + r) * Ndim + col] = v;
      }
    }
  }
}

// ---------------- V transpose: vt[bh][d][t] from qkv ----------------
__global__ void k_vt(const u16* __restrict__ qkv, u16* __restrict__ vt){
  __shared__ u16 tl[64][50];
  int t0 = blockIdx.x * 64;
  int bh = blockIdx.y; int b = bh >> 4, h = bh & 15;
  int tid = threadIdx.x;
  for (int i = tid; i < 64*48; i += 256){
    int tt = i / 48, d = i % 48;
    tl[tt][d] = qkv[(size_t)(b*T_ + t0 + tt) * N3_ + 2*C_ + h*D_ + d];
  }
  __syncthreads();
  for (int i = tid; i < 48*64; i += 256){
    int d = i >> 6, tt = i & 63;
    vt[(size_t)(bh*D_ + d) * T_ + t0 + tt] = tl[tt][d];
  }
}

// ---------------- causal flash attention, paired q-tiles ----------------
// grid: 1024 blocks (XCD-swizzled); block = 256 (4 waves). Each block owns
// q-tiles (qbA=pair, qbB=31-pair) -> uniform 33 tile-units of work. Per K-tile,
// K-fragments are read once and feed both q-tiles' QK^T. Row reduces use DPP
// (VALU) instead of shfl (LDS). One barrier per K-tile, double-buffered K/V.
__launch_bounds__(256)
__global__ void k_attn(const u16* __restrict__ qkv, const u16* __restrict__ vt,
                       u16* __restrict__ ao){
  __shared__ u16 lK[2][64*64];   // 64 rows x 128B (96B valid + 32B garbage pad)
  __shared__ u16 lV[2][48*64];   // 48 d-rows x 128B (64 keys)
  __shared__ u16 lP[4][16*64];   // per-wave 16 rows x 128B, swizzled (reused A/B)

  const int wg = ((blockIdx.x & 7) << 7) + (blockIdx.x >> 3);   // 8 XCDs x 128
  const int pairI = wg & 15, bh = wg >> 4;
  const int qbA = pairI, qbB = 31 - pairI;
  const int b = bh >> 4, h = bh & 15;
  const int tid = threadIdx.x, lane = tid & 63, w = tid >> 6;
  const int ls = lane & 15, hi = lane >> 4;
  const f32x4 fzero = {0.f, 0.f, 0.f, 0.f};
  const bf16x8 bzero = {0, 0, 0, 0, 0, 0, 0, 0};
  const float scale2 = 0.20823527f;    // 48^-0.5 * log2(e)

  // ---- Q fragments for both q-tiles (one-time, direct from global) ----
  bf16x8 aqA[2], aqB[2];
  {
    const u16* qpA = qkv + (size_t)(b*T_ + qbA*64 + w*16 + ls) * N3_ + h*D_ + hi*8;
    aqA[0] = *(const bf16x8*)qpA;
    aqA[1] = (hi < 2) ? *(const bf16x8*)(qpA + 32) : bzero;
    const u16* qpB = qkv + (size_t)(b*T_ + qbB*64 + w*16 + ls) * N3_ + h*D_ + hi*8;
    aqB[0] = *(const bf16x8*)qpB;
    aqB[1] = (hi < 2) ? *(const bf16x8*)(qpB + 32) : bzero;
  }

  // ---- staging source addresses (inverse-swizzled, linear LDS dest) ----
  const char* kg0; const char* kg1; const char* vg0; const char* vg1;
  {
    int c0 = tid,        r0 = c0 >> 3, cb0 = ((c0 & 7) << 4) ^ ((r0 & 7) << 4);
    int c1 = tid + 256,  r1 = c1 >> 3, cb1 = ((c1 & 7) << 4) ^ ((r1 & 7) << 4);
    kg0 = (const char*)(qkv + (size_t)(b*T_ + r0) * N3_ + C_ + h*D_) + cb0;
    kg1 = (const char*)(qkv + (size_t)(b*T_ + r1) * N3_ + C_ + h*D_) + cb1;
    vg0 = (const char*)(vt + (size_t)(bh*D_ + r0) * T_) + cb0;
    vg1 = (const char*)(vt + (size_t)(bh*D_ + (tid < 128 ? r1 : 0)) * T_) + cb1;
  }
  const size_t kstep = (size_t)64 * N3_ * 2;
  const size_t vstep = (size_t)64 * 2;

  auto STAGE = [&](int kb, int buf){
    const size_t ko = (size_t)kb * kstep, vo = (size_t)kb * vstep;
    __builtin_amdgcn_global_load_lds((gptr_t)(kg0 + ko),
        (lptr_t)((char*)lK[buf] + (tid << 4)), 16, 0, 0);
    __builtin_amdgcn_global_load_lds((gptr_t)(kg1 + ko),
        (lptr_t)((char*)lK[buf] + ((tid + 256) << 4)), 16, 0, 0);
    __builtin_amdgcn_global_load_lds((gptr_t)(vg0 + vo),
        (lptr_t)((char*)lV[buf] + (tid << 4)), 16, 0, 0);
    if (tid < 128)
      __builtin_amdgcn_global_load_lds((gptr_t)(vg1 + vo),
          (lptr_t)((char*)lV[buf] + ((tid + 256) << 4)), 16, 0, 0);
  };

  float mrunA[4], lsumA[4], mrunB[4], lsumB[4];
  f32x4 oaccA[3], oaccB[3];
  #pragma unroll
  for (int i = 0; i < 4; ++i){ mrunA[i] = -1e30f; lsumA[i] = 0.f;
                               mrunB[i] = -1e30f; lsumB[i] = 0.f; }
  #pragma unroll
  for (int nf = 0; nf < 3; ++nf){ oaccA[nf] = fzero; oaccB[nf] = fzero; }

  int cur = 0;

  // softmax + P-write + PV for one q-tile's 64-key strip
  auto softmax_pv = [&](f32x4 (&s)[4], float (&mrun)[4], float (&lsum)[4],
                        f32x4 (&oacc)[3], int qt, bool diag, int krow0){
    #pragma unroll
    for (int nf = 0; nf < 4; ++nf)
      #pragma unroll
      for (int r = 0; r < 4; ++r)
        s[nf][r] *= scale2;
    if (diag){
      #pragma unroll
      for (int r = 0; r < 4; ++r){
        int qg = qt + w*16 + hi*4 + r;
        #pragma unroll
        for (int nf = 0; nf < 4; ++nf){
          int kg = krow0 + nf*16 + ls;
          s[nf][r] = (kg <= qg) ? s[nf][r] : -1e30f;
        }
      }
    }
    float rmax[4];
    #pragma unroll
    for (int r = 0; r < 4; ++r)
      rmax[r] = rowmax16(fmaxf(fmaxf(s[0][r], s[1][r]), fmaxf(s[2][r], s[3][r])));
    bool grow = (rmax[0] > mrun[0]) | (rmax[1] > mrun[1]) |
                (rmax[2] > mrun[2]) | (rmax[3] > mrun[3]);
    if (__any(grow)){
      float corr[4];
      #pragma unroll
      for (int r = 0; r < 4; ++r){
        float mn = fmaxf(mrun[r], rmax[r]);
        corr[r] = __builtin_amdgcn_exp2f(mrun[r] - mn);
        mrun[r] = mn;
        lsum[r] *= corr[r];
      }
      #pragma unroll
      for (int nf = 0; nf < 3; ++nf)
        #pragma unroll
        for (int r = 0; r < 4; ++r)
          oacc[nf][r] *= corr[r];
    }
    #pragma unroll
    for (int nf = 0; nf < 4; ++nf)
      #pragma unroll
      for (int r = 0; r < 4; ++r){
        float e = __builtin_amdgcn_exp2f(s[nf][r] - mrun[r]);
        s[nf][r] = e;
        lsum[r] += e;
      }
    u16* myP = &lP[w][0];
    #pragma unroll
    for (int r = 0; r < 4; ++r){
      int prow = hi*4 + r;
      int sw = (prow & 7) << 4;
      char* rowp = (char*)myP + (prow << 7);
      #pragma unroll
      for (int nf = 0; nf < 4; ++nf)
        *(u16*)(rowp + (((nf*16 + ls) << 1) ^ sw)) = f2b(s[nf][r]);
    }
    #pragma unroll
    for (int kk = 0; kk < 2; ++kk){
      int kbyte = (kk << 6) + (hi << 4);
      bf16x8 pa = ld_frag(myP, ls, kbyte);
      #pragma unroll
      for (int nf = 0; nf < 3; ++nf){
        bf16x8 bv = ld_frag(lV[cur], nf*16 + ls, kbyte);
        oacc[nf] = __builtin_amdgcn_mfma_f32_16x16x32_bf16(pa, bv, oacc[nf], 0, 0, 0);
      }
    }
  };

  const int kbmax = qbB;
  STAGE(0, 0);
  __syncthreads();

  for (int kb = 0; kb <= kbmax; ++kb){
    if (kb < kbmax) STAGE(kb + 1, cur ^ 1);
    const bool actA = (kb <= qbA);

    f32x4 sA[4], sB[4];
    #pragma unroll
    for (int nf = 0; nf < 4; ++nf){ sA[nf] = fzero; sB[nf] = fzero; }
    #pragma unroll
    for (int kk = 0; kk < 2; ++kk){
      int kbyte = (kk << 6) + (hi << 4);
      #pragma unroll
      for (int nf = 0; nf < 4; ++nf){
        bf16x8 bk = ld_frag(lK[cur], nf*16 + ls, kbyte);
        sB[nf] = __builtin_amdgcn_mfma_f32_16x16x32_bf16(aqB[kk], bk, sB[nf], 0, 0, 0);
        if (actA)
          sA[nf] = __builtin_amdgcn_mfma_f32_16x16x32_bf16(aqA[kk], bk, sA[nf], 0, 0, 0);
      }
    }

    if (actA) softmax_pv(sA, mrunA, lsumA, oaccA, qbA*64, kb == qbA, kb*64);
    softmax_pv(sB, mrunB, lsumB, oaccB, qbB*64, kb == qbB, kb*64);

    if (kb < kbmax){
      __syncthreads();
      cur ^= 1;
    }
  }

  // ---- epilogue: finish deferred sum reduce (DPP), normalize, store ----
  #pragma unroll
  for (int r = 0; r < 4; ++r){
    float invA = 1.f / rowsum16(lsumA[r]);
    float invB = 1.f / rowsum16(lsumB[r]);
    int tA = qbA*64 + w*16 + hi*4 + r;
    int tB = qbB*64 + w*16 + hi*4 + r;
    #pragma unroll
    for (int nf = 0; nf < 3; ++nf){
      int col = h*D_ + nf*16 + ls;
      ao[(size_t)(b*T_ + tA) * C_ + col] = f2b(oaccA[nf][r] * invA);
      ao[(size_t)(b*T_ + tB) * C_ + col] = f2b(oaccB[nf][r] * invB);
    }
  }
}

extern "C" void kernel_launch(void* const* d_in, const int* in_sizes, int n_in,
                              void* d_out, int out_size, void* d_ws, size_t ws_size,
                              hipStream_t stream){
  if (n_in < 4) return;
  const float* x      = (const float*)d_in[0];
  const float* W_attn = (const float*)d_in[1];
  const float* W_proj = (const float*)d_in[2];
  const float* b_proj = (const float*)d_in[3];

  char* ws = (char*)d_ws;
  size_t off = 0;
  auto alloc = [&](size_t bytes)->void*{
    void* p = ws + off; off += (bytes + 255) & ~(size_t)255; return p;
  };
  u16* xb   = (u16*)alloc((size_t)M_ * C_  * 2);
  u16* wabT = (u16*)alloc((size_t)N3_ * C_ * 2);
  u16* wpbT = (u16*)alloc((size_t)C_ * C_  * 2);
  u16* qkv  = (u16*)alloc((size_t)M_ * N3_ * 2);
  u16* vt   = (u16*)alloc((size_t)B_ * H_ * D_ * T_ * 2);
  u16* ao   = (u16*)alloc((size_t)M_ * C_  * 2);
  if (off > ws_size) return;  // workspace too small — bail cleanly

  k_cvt<<<dim3((M_*C_/4 + 255)/256), dim3(256), 0, stream>>>(x, xb, M_*C_/4);
  k_tpose<<<dim3(N3_/32, C_/32), dim3(256), 0, stream>>>(W_attn, wabT, C_, N3_);
  k_tpose<<<dim3(C_/32,  C_/32), dim3(256), 0, stream>>>(W_proj, wpbT, C_, C_);
  k_gemm<true,false><<<dim3(M_/128, N3_/128), dim3(256), 0, stream>>>(
      xb, wabT, (void*)qkv, (const float*)nullptr, N3_, C_);
  k_vt<<<dim3(T_/64, B_*H_), dim3(256), 0, stream>>>(qkv, vt);
  k_attn<<<dim3(1024), dim3(256), 0, stream>>>(qkv, vt, ao);
  k_gemm<false,true><<<dim3(M_/128, C_/128), dim3(256), 0, stream>>>(
      ao, wpbT, d_out, b_proj, C_, C_);
}

// Round 7
// 191.067 us; speedup vs baseline: 2.3232x; 1.0113x over previous
//
#include <hip/hip_runtime.h>
#include <cstdint>
#include <cstddef>

#define B_ 4
#define T_ 2048
#define C_ 768
#define H_ 16
#define D_ 48
#define M_ (B_*T_)      // 8192
#define N3_ (3*C_)      // 2304

typedef unsigned short u16;
typedef __attribute__((ext_vector_type(8))) short bf16x8;
typedef __attribute__((ext_vector_type(4))) float f32x4;
typedef __attribute__((ext_vector_type(4))) unsigned int u32x4;
typedef __attribute__((ext_vector_type(4))) unsigned short u16x4;

typedef const __attribute__((address_space(1))) unsigned int* gptr_t;
typedef __attribute__((address_space(3))) unsigned int* lptr_t;

__device__ __forceinline__ u16 f2b(float f){
  union { float f; unsigned u; } x; x.f = f;
  unsigned u = x.u;
  return (u16)((u + 0x7FFFu + ((u >> 16) & 1u)) >> 16);
}

// v_cvt_pk_bf16_f32: packs {bf16(lo), bf16(hi)} into one u32 (RNE).
__device__ __forceinline__ unsigned cvtpk(float lo, float hi){
  unsigned r;
  asm("v_cvt_pk_bf16_f32 %0, %1, %2" : "=v"(r) : "v"(lo), "v"(hi));
  return r;
}

// Swizzled LDS fragment load. All LDS tiles use 128-byte row pitch.
// Physical byte = row*128 + (col_byte ^ ((row&7)<<4)).
__device__ __forceinline__ bf16x8 ld_frag(const u16* lds, int row, int kbyte){
  const char* p = (const char*)lds + (row << 7) + (kbyte ^ ((row & 7) << 4));
  return *(const bf16x8*)p;
}

// ---------------- fp32 -> bf16 convert (vectorized x4) ----------------
__global__ void k_cvt(const float* __restrict__ in, u16* __restrict__ out, int n4){
  int i = blockIdx.x * blockDim.x + threadIdx.x;
  if (i >= n4) return;
  f32x4 v = *(const f32x4*)(in + 4*(size_t)i);
  u16x4 o;
  o.x = f2b(v.x); o.y = f2b(v.y); o.z = f2b(v.z); o.w = f2b(v.w);
  *(u16x4*)(out + 4*(size_t)i) = o;
}

// ------ fp32 [R][Cn] -> bf16 transposed [Cn][R]; rows < scaleRows get *scl ------
__global__ void k_tpose(const float* __restrict__ in, u16* __restrict__ out, int R, int Cn,
                        int scaleRows, float scl){
  __shared__ float tile[32][33];
  int tx = threadIdx.x & 31, ty = threadIdx.x >> 5;  // ty 0..7
  int c  = blockIdx.x * 32 + tx;
  int rb = blockIdx.y * 32;
  #pragma unroll
  for (int r0 = 0; r0 < 32; r0 += 8)
    tile[ty + r0][tx] = in[(size_t)(rb + ty + r0) * Cn + c];
  __syncthreads();
  int oc = rb + tx;
  int cb = blockIdx.x * 32;
  #pragma unroll
  for (int r0 = 0; r0 < 32; r0 += 8){
    float v = tile[tx][ty + r0];
    if (cb + ty + r0 < scaleRows) v *= scl;
    out[(size_t)(cb + ty + r0) * R + oc] = f2b(v);
  }
}

// ---------------- bf16 GEMM: C[m][n] = sum_k A[m][k]*Bt[n][k] ----------------
template<bool OUT_BF16, bool ADD_BIAS>
__launch_bounds__(256)
__global__ void k_gemm(const u16* __restrict__ A, const u16* __restrict__ Bt,
                       void* __restrict__ Cout, const float* __restrict__ bias,
                       int Ndim, int Kdim){
  __shared__ u16 lA[128*64];
  __shared__ u16 lB[128*64];
  const int tid = threadIdx.x, lane = tid & 63, w = tid >> 6;
  const int m0 = blockIdx.x * 128, n0 = blockIdx.y * 128;
  const int wr = (w >> 1) * 64, wc = (w & 1) * 64;
  const f32x4 fzero = {0.f, 0.f, 0.f, 0.f};
  f32x4 acc[4][4];
  #pragma unroll
  for (int i = 0; i < 4; ++i)
    #pragma unroll
    for (int j = 0; j < 4; ++j) acc[i][j] = fzero;

  for (int k0 = 0; k0 < Kdim; k0 += 64){
    __syncthreads();
    #pragma unroll
    for (int it = 0; it < 4; ++it){
      int c = tid + it * 256;              // 0..1023
      int row  = c >> 3;
      int cb   = (c & 7) << 4;
      int pcol = cb ^ ((row & 7) << 4);
      const char* ga = (const char*)(A  + (size_t)(m0 + row) * Kdim + k0) + pcol;
      const char* gb = (const char*)(Bt + (size_t)(n0 + row) * Kdim + k0) + pcol;
      __builtin_amdgcn_global_load_lds((gptr_t)ga, (lptr_t)((char*)lA + (c << 4)), 16, 0, 0);
      __builtin_amdgcn_global_load_lds((gptr_t)gb, (lptr_t)((char*)lB + (c << 4)), 16, 0, 0);
    }
    __syncthreads();
    #pragma unroll
    for (int kk = 0; kk < 2; ++kk){
      int kbyte = (kk << 6) + ((lane >> 4) << 4);
      bf16x8 af[4], bfv[4];
      #pragma unroll
      for (int i = 0; i < 4; ++i){
        af[i]  = ld_frag(lA, wr + i*16 + (lane & 15), kbyte);
        bfv[i] = ld_frag(lB, wc + i*16 + (lane & 15), kbyte);
      }
      #pragma unroll
      for (int i = 0; i < 4; ++i)
        #pragma unroll
        for (int j = 0; j < 4; ++j)
          acc[i][j] = __builtin_amdgcn_mfma_f32_16x16x32_bf16(af[i], bfv[j], acc[i][j], 0, 0, 0);
    }
  }
  #pragma unroll
  for (int i = 0; i < 4; ++i){
    int rbase = m0 + wr + i*16 + ((lane >> 4) << 2);
    #pragma unroll
    for (int j = 0; j < 4; ++j){
      int col = n0 + wc + j*16 + (lane & 15);
      float bv = ADD_BIAS ? bias[col] : 0.f;
      #pragma unroll
      for (int r = 0; r < 4; ++r){
        float v = acc[i][j][r] + bv;
        if (OUT_BF16) ((u16*)Cout)[(size_t)(rbase + r) * Ndim + col] = f2b(v);
        else          ((float*)Cout)[(size_t)(rbase + r) * Ndim + col] = v;
      }
    }
  }
}

// ---------------- V transpose: vt[bh][d][t] from qkv ----------------
__global__ void k_vt(const u16* __restrict__ qkv, u16* __restrict__ vt){
  __shared__ u16 tl[64][50];
  int t0 = blockIdx.x * 64;
  int bh = blockIdx.y; int b = bh >> 4, h = bh & 15;
  int tid = threadIdx.x;
  for (int i = tid; i < 64*48; i += 256){
    int tt = i / 48, d = i % 48;
    tl[tt][d] = qkv[(size_t)(b*T_ + t0 + tt) * N3_ + 2*C_ + h*D_ + d];
  }
  __syncthreads();
  for (int i = tid; i < 48*64; i += 256){
    int d = i >> 6, tt = i & 63;
    vt[(size_t)(bh*D_ + d) * T_ + t0 + tt] = tl[tt][d];
  }
}

// ---------------- causal flash attention, swapped-operand MFMA ----------------
// grid: 1024 blocks (XCD-swizzled); block = 256 (4 waves). Block owns q-tiles
// (qbA, 31-qbA). QK^T computed SWAPPED (S^T = K*Q^T) so each lane holds 16
// S-values for ONE q-row (q = lane&15): softmax is in-lane + 2 shfl. P stays
// in registers (8 cvt_pk), PV computed swapped (O^T = V^T*P^T) with V columns
// sigma-permuted at staging time so the register P order is the MFMA k-order.
__launch_bounds__(256)
__global__ void k_attn(const u16* __restrict__ qkv, const u16* __restrict__ vt,
                       u16* __restrict__ ao){
  __shared__ u16 lK[2][64*64];   // 64 key-rows x 128B (96B valid + 32B garbage)
  __shared__ u16 lV[2][48*64];   // 48 d-rows x 128B (64 sigma-permuted keys)

  const int wg = ((blockIdx.x & 7) << 7) + (blockIdx.x >> 3);   // 8 XCDs x 128
  const int pairI = wg & 15, bh = wg >> 4;
  const int qbA = pairI, qbB = 31 - pairI;
  const int b = bh >> 4, h = bh & 15;
  const int tid = threadIdx.x, lane = tid & 63, w = tid >> 6;
  const int ls = lane & 15, hi = lane >> 4;
  const f32x4 fzero = {0.f, 0.f, 0.f, 0.f};
  const bf16x8 bzero = {0, 0, 0, 0, 0, 0, 0, 0};

  // ---- Q fragments (B-operand layout == old A layout; Q pre-scaled in W) ----
  bf16x8 aqA[2], aqB[2];
  {
    const u16* qpA = qkv + (size_t)(b*T_ + qbA*64 + w*16 + ls) * N3_ + h*D_ + hi*8;
    aqA[0] = *(const bf16x8*)qpA;
    aqA[1] = (hi < 2) ? *(const bf16x8*)(qpA + 32) : bzero;
    const u16* qpB = qkv + (size_t)(b*T_ + qbB*64 + w*16 + ls) * N3_ + h*D_ + hi*8;
    aqB[0] = *(const bf16x8*)qpB;
    aqB[1] = (hi < 2) ? *(const bf16x8*)(qpB + 32) : bzero;
  }

  // ---- staging addresses ----
  const char* kg0; const char* kg1; const char* vg;
  {
    int c0 = tid,        r0 = c0 >> 3, cb0 = ((c0 & 7) << 4) ^ ((r0 & 7) << 4);
    int c1 = tid + 256,  r1 = c1 >> 3, cb1 = ((c1 & 7) << 4) ^ ((r1 & 7) << 4);
    kg0 = (const char*)(qkv + (size_t)(b*T_ + r0) * N3_ + C_ + h*D_) + cb0;
    kg1 = (const char*)(qkv + (size_t)(b*T_ + r1) * N3_ + C_ + h*D_) + cb1;
    // V: width-4 chunks; thread handles d-rows d0, d0+8, ..., d0+40 at one
    // fixed in-row position. logical col k from unswizzle; source key = sigma(k).
    int d0  = tid >> 5;                 // 0..7
    int pb4 = (tid << 2) & 127;         // physical byte in 128B row
    int lb  = pb4 ^ (d0 << 4);          // logical byte (d&7 == d0 for all it)
    int k   = lb >> 1;                  // even logical column
    int sk  = (k & 0x23) | ((k & 4) << 2) | ((k & 0x18) >> 1);  // sigma(k)
    vg = (const char*)(vt + (size_t)(bh*D_ + d0) * T_) + (sk << 1);
  }
  const size_t kstep = (size_t)64 * N3_ * 2;

  auto STAGE = [&](int kb, int buf){
    const size_t ko = (size_t)kb * kstep;
    const int vo = kb * 128;
    __builtin_amdgcn_global_load_lds((gptr_t)(kg0 + ko),
        (lptr_t)((char*)lK[buf] + (tid << 4)), 16, 0, 0);
    __builtin_amdgcn_global_load_lds((gptr_t)(kg1 + ko),
        (lptr_t)((char*)lK[buf] + ((tid + 256) << 4)), 16, 0, 0);
    #pragma unroll
    for (int it = 0; it < 6; ++it)
      __builtin_amdgcn_global_load_lds((gptr_t)(vg + vo + it * (8 * T_ * 2)),
          (lptr_t)((char*)lV[buf] + ((tid + it*256) << 2)), 4, 0, 0);
  };

  float mrunA = -1e30f, lsumA = 0.f, mrunB = -1e30f, lsumB = 0.f;
  f32x4 oaccA[3], oaccB[3];
  #pragma unroll
  for (int nf = 0; nf < 3; ++nf){ oaccA[nf] = fzero; oaccB[nf] = fzero; }

  int cur = 0;

  // softmax on S^T regs: s[nf][r] = S[key=16nf+4hi+r][q=ls]. Emits P frags.
  auto softmax = [&](f32x4 (&s)[4], float &mrun, float &lsum, f32x4 (&oacc)[3],
                     bf16x8 &pb0, bf16x8 &pb1, bool diag, int krow0, int qt){
    if (diag){
      int qg = qt + w*16 + ls;
      #pragma unroll
      for (int nf = 0; nf < 4; ++nf)
        #pragma unroll
        for (int r = 0; r < 4; ++r){
          int kg = krow0 + nf*16 + hi*4 + r;
          s[nf][r] = (kg <= qg) ? s[nf][r] : -1e30f;
        }
    }
    float m0 = fmaxf(fmaxf(s[0][0], s[0][1]), fmaxf(s[0][2], s[0][3]));
    float m1 = fmaxf(fmaxf(s[1][0], s[1][1]), fmaxf(s[1][2], s[1][3]));
    float m2 = fmaxf(fmaxf(s[2][0], s[2][1]), fmaxf(s[2][2], s[2][3]));
    float m3 = fmaxf(fmaxf(s[3][0], s[3][1]), fmaxf(s[3][2], s[3][3]));
    float mx = fmaxf(fmaxf(m0, m1), fmaxf(m2, m3));
    mx = fmaxf(mx, __shfl_xor(mx, 16));
    mx = fmaxf(mx, __shfl_xor(mx, 32));
    if (__any(mx > mrun)){
      float mn = fmaxf(mrun, mx);
      float corr = __builtin_amdgcn_exp2f(mrun - mn);
      mrun = mn;
      lsum *= corr;
      #pragma unroll
      for (int nf = 0; nf < 3; ++nf)
        #pragma unroll
        for (int r = 0; r < 4; ++r)
          oacc[nf][r] *= corr;
    }
    float p[4][4];
    #pragma unroll
    for (int nf = 0; nf < 4; ++nf)
      #pragma unroll
      for (int r = 0; r < 4; ++r){
        float e = __builtin_amdgcn_exp2f(s[nf][r] - mrun);
        p[nf][r] = e;
        lsum += e;
      }
    union { u32x4 u; bf16x8 b; } w0, w1;
    w0.u.x = cvtpk(p[0][0], p[0][1]); w0.u.y = cvtpk(p[0][2], p[0][3]);
    w0.u.z = cvtpk(p[1][0], p[1][1]); w0.u.w = cvtpk(p[1][2], p[1][3]);
    w1.u.x = cvtpk(p[2][0], p[2][1]); w1.u.y = cvtpk(p[2][2], p[2][3]);
    w1.u.z = cvtpk(p[3][0], p[3][1]); w1.u.w = cvtpk(p[3][2], p[3][3]);
    pb0 = w0.b; pb1 = w1.b;
  };

  const int kbmax = qbB;
  STAGE(0, 0);
  __syncthreads();

  for (int kb = 0; kb <= kbmax; ++kb){
    if (kb < kbmax) STAGE(kb + 1, cur ^ 1);
    const bool actA = (kb <= qbA);

    // ---- S^T = K * Q^T (swapped operands; shared K-fragment reads) ----
    f32x4 stA[4], stB[4];
    #pragma unroll
    for (int nf = 0; nf < 4; ++nf){ stA[nf] = fzero; stB[nf] = fzero; }
    #pragma unroll
    for (int kk = 0; kk < 2; ++kk){
      int kbyte = (kk << 6) + (hi << 4);
      #pragma unroll
      for (int nf = 0; nf < 4; ++nf){
        bf16x8 bk = ld_frag(lK[cur], nf*16 + ls, kbyte);
        stB[nf] = __builtin_amdgcn_mfma_f32_16x16x32_bf16(bk, aqB[kk], stB[nf], 0, 0, 0);
        if (actA)
          stA[nf] = __builtin_amdgcn_mfma_f32_16x16x32_bf16(bk, aqA[kk], stA[nf], 0, 0, 0);
      }
    }

    bf16x8 pbA0, pbA1, pbB0, pbB1;
    if (actA) softmax(stA, mrunA, lsumA, oaccA, pbA0, pbA1, kb == qbA, kb*64, qbA*64);
    softmax(stB, mrunB, lsumB, oaccB, pbB0, pbB1, kb == qbB, kb*64, qbB*64);

    // ---- O^T += V^T * P^T (swapped; shared V-fragment reads) ----
    #pragma unroll
    for (int kk = 0; kk < 2; ++kk){
      int kbyte = (kk << 6) + (hi << 4);
      #pragma unroll
      for (int nf = 0; nf < 3; ++nf){
        bf16x8 bv = ld_frag(lV[cur], nf*16 + ls, kbyte);
        oaccB[nf] = __builtin_amdgcn_mfma_f32_16x16x32_bf16(
            bv, kk ? pbB1 : pbB0, oaccB[nf], 0, 0, 0);
        if (actA)
          oaccA[nf] = __builtin_amdgcn_mfma_f32_16x16x32_bf16(
              bv, kk ? pbA1 : pbA0, oaccA[nf], 0, 0, 0);
      }
    }

    if (kb < kbmax){
      __syncthreads();
      cur ^= 1;
    }
  }

  // ---- epilogue: finish lsum across hi-groups, normalize, store O^T ----
  float lA = lsumA; lA += __shfl_xor(lA, 16); lA += __shfl_xor(lA, 32);
  float lB = lsumB; lB += __shfl_xor(lB, 16); lB += __shfl_xor(lB, 32);
  float invA = 1.f / lA, invB = 1.f / lB;
  int tA = qbA*64 + w*16 + ls, tB = qbB*64 + w*16 + ls;
  #pragma unroll
  for (int nf = 0; nf < 3; ++nf){
    u16x4 oA, oB;
    #pragma unroll
    for (int r = 0; r < 4; ++r){
      oA[r] = f2b(oaccA[nf][r] * invA);   // O[q=ls][d = nf*16 + 4hi + r]
      oB[r] = f2b(oaccB[nf][r] * invB);
    }
    int col = h*D_ + nf*16 + hi*4;
    *(u16x4*)(ao + (size_t)(b*T_ + tA) * C_ + col) = oA;
    *(u16x4*)(ao + (size_t)(b*T_ + tB) * C_ + col) = oB;
  }
}

extern "C" void kernel_launch(void* const* d_in, const int* in_sizes, int n_in,
                              void* d_out, int out_size, void* d_ws, size_t ws_size,
                              hipStream_t stream){
  if (n_in < 4) return;
  const float* x      = (const float*)d_in[0];
  const float* W_attn = (const float*)d_in[1];
  const float* W_proj = (const float*)d_in[2];
  const float* b_proj = (const float*)d_in[3];

  char* ws = (char*)d_ws;
  size_t off = 0;
  auto alloc = [&](size_t bytes)->void*{
    void* p = ws + off; off += (bytes + 255) & ~(size_t)255; return p;
  };
  u16* xb   = (u16*)alloc((size_t)M_ * C_  * 2);
  u16* wabT = (u16*)alloc((size_t)N3_ * C_ * 2);
  u16* wpbT = (u16*)alloc((size_t)C_ * C_  * 2);
  u16* qkv  = (u16*)alloc((size_t)M_ * N3_ * 2);
  u16* vt   = (u16*)alloc((size_t)B_ * H_ * D_ * T_ * 2);
  u16* ao   = (u16*)alloc((size_t)M_ * C_  * 2);
  if (off > ws_size) return;  // workspace too small — bail cleanly

  const float scale2 = 0.20823527f;    // 48^-0.5 * log2(e), folded into W_attn Q-cols

  k_cvt<<<dim3((M_*C_/4 + 255)/256), dim3(256), 0, stream>>>(x, xb, M_*C_/4);
  k_tpose<<<dim3(N3_/32, C_/32), dim3(256), 0, stream>>>(W_attn, wabT, C_, N3_, C_, scale2);
  k_tpose<<<dim3(C_/32,  C_/32), dim3(256), 0, stream>>>(W_proj, wpbT, C_, C_, 0, 1.f);
  k_gemm<true,false><<<dim3(M_/128, N3_/128), dim3(256), 0, stream>>>(
      xb, wabT, (void*)qkv, (const float*)nullptr, N3_, C_);
  k_vt<<<dim3(T_/64, B_*H_), dim3(256), 0, stream>>>(qkv, vt);
  k_attn<<<dim3(1024), dim3(256), 0, stream>>>(qkv, vt, ao);
  k_gemm<false,true><<<dim3(M_/128, C_/128), dim3(256), 0, stream>>>(
      ao, wpbT, d_out, b_proj, C_, C_);
}

// Round 8
// 170.585 us; speedup vs baseline: 2.6021x; 1.1201x over previous
//
#include <hip/hip_runtime.h>
#include <cstdint>
#include <cstddef>

#define B_ 4
#define T_ 2048
#define C_ 768
#define H_ 16
#define D_ 48
#define M_ (B_*T_)      // 8192
#define N3_ (3*C_)      // 2304

typedef unsigned short u16;
typedef __attribute__((ext_vector_type(8))) short bf16x8;
typedef __attribute__((ext_vector_type(4))) float f32x4;
typedef __attribute__((ext_vector_type(4))) unsigned int u32x4;
typedef __attribute__((ext_vector_type(4))) unsigned short u16x4;

typedef const __attribute__((address_space(1))) unsigned int* gptr_t;
typedef __attribute__((address_space(3))) unsigned int* lptr_t;

__device__ __forceinline__ u16 f2b(float f){
  union { float f; unsigned u; } x; x.f = f;
  unsigned u = x.u;
  return (u16)((u + 0x7FFFu + ((u >> 16) & 1u)) >> 16);
}

// v_cvt_pk_bf16_f32: packs {bf16(lo), bf16(hi)} into one u32 (RNE).
__device__ __forceinline__ unsigned cvtpk(float lo, float hi){
  unsigned r;
  asm("v_cvt_pk_bf16_f32 %0, %1, %2" : "=v"(r) : "v"(lo), "v"(hi));
  return r;
}

// Swizzled LDS fragment load. All LDS tiles use 128-byte row pitch.
// Physical byte = row*128 + (col_byte ^ ((row&7)<<4)).
__device__ __forceinline__ bf16x8 ld_frag(const u16* lds, int row, int kbyte){
  const char* p = (const char*)lds + (row << 7) + (kbyte ^ ((row & 7) << 4));
  return *(const bf16x8*)p;
}

// ---------------- fp32 -> bf16 convert (vectorized x4) ----------------
__global__ void k_cvt(const float* __restrict__ in, u16* __restrict__ out, int n4){
  int i = blockIdx.x * blockDim.x + threadIdx.x;
  if (i >= n4) return;
  f32x4 v = *(const f32x4*)(in + 4*(size_t)i);
  u16x4 o;
  o.x = f2b(v.x); o.y = f2b(v.y); o.z = f2b(v.z); o.w = f2b(v.w);
  *(u16x4*)(out + 4*(size_t)i) = o;
}

// ------ fp32 [R][Cn] -> bf16 transposed [Cn][R]; rows < scaleRows get *scl ------
__global__ void k_tpose(const float* __restrict__ in, u16* __restrict__ out, int R, int Cn,
                        int scaleRows, float scl){
  __shared__ float tile[32][33];
  int tx = threadIdx.x & 31, ty = threadIdx.x >> 5;  // ty 0..7
  int c  = blockIdx.x * 32 + tx;
  int rb = blockIdx.y * 32;
  #pragma unroll
  for (int r0 = 0; r0 < 32; r0 += 8)
    tile[ty + r0][tx] = in[(size_t)(rb + ty + r0) * Cn + c];
  __syncthreads();
  int oc = rb + tx;
  int cb = blockIdx.x * 32;
  #pragma unroll
  for (int r0 = 0; r0 < 32; r0 += 8){
    float v = tile[tx][ty + r0];
    if (cb + ty + r0 < scaleRows) v *= scl;
    out[(size_t)(cb + ty + r0) * R + oc] = f2b(v);
  }
}

// ---------------- bf16 GEMM: C[m][n] = sum_k A[m][k]*Bt[n][k] ----------------
template<bool OUT_BF16, bool ADD_BIAS>
__launch_bounds__(256)
__global__ void k_gemm(const u16* __restrict__ A, const u16* __restrict__ Bt,
                       void* __restrict__ Cout, const float* __restrict__ bias,
                       int Ndim, int Kdim){
  __shared__ u16 lA[128*64];
  __shared__ u16 lB[128*64];
  const int tid = threadIdx.x, lane = tid & 63, w = tid >> 6;
  const int m0 = blockIdx.x * 128, n0 = blockIdx.y * 128;
  const int wr = (w >> 1) * 64, wc = (w & 1) * 64;
  const f32x4 fzero = {0.f, 0.f, 0.f, 0.f};
  f32x4 acc[4][4];
  #pragma unroll
  for (int i = 0; i < 4; ++i)
    #pragma unroll
    for (int j = 0; j < 4; ++j) acc[i][j] = fzero;

  for (int k0 = 0; k0 < Kdim; k0 += 64){
    __syncthreads();
    #pragma unroll
    for (int it = 0; it < 4; ++it){
      int c = tid + it * 256;              // 0..1023
      int row  = c >> 3;
      int cb   = (c & 7) << 4;
      int pcol = cb ^ ((row & 7) << 4);
      const char* ga = (const char*)(A  + (size_t)(m0 + row) * Kdim + k0) + pcol;
      const char* gb = (const char*)(Bt + (size_t)(n0 + row) * Kdim + k0) + pcol;
      __builtin_amdgcn_global_load_lds((gptr_t)ga, (lptr_t)((char*)lA + (c << 4)), 16, 0, 0);
      __builtin_amdgcn_global_load_lds((gptr_t)gb, (lptr_t)((char*)lB + (c << 4)), 16, 0, 0);
    }
    __syncthreads();
    #pragma unroll
    for (int kk = 0; kk < 2; ++kk){
      int kbyte = (kk << 6) + ((lane >> 4) << 4);
      bf16x8 af[4], bfv[4];
      #pragma unroll
      for (int i = 0; i < 4; ++i){
        af[i]  = ld_frag(lA, wr + i*16 + (lane & 15), kbyte);
        bfv[i] = ld_frag(lB, wc + i*16 + (lane & 15), kbyte);
      }
      #pragma unroll
      for (int i = 0; i < 4; ++i)
        #pragma unroll
        for (int j = 0; j < 4; ++j)
          acc[i][j] = __builtin_amdgcn_mfma_f32_16x16x32_bf16(af[i], bfv[j], acc[i][j], 0, 0, 0);
    }
  }
  #pragma unroll
  for (int i = 0; i < 4; ++i){
    int rbase = m0 + wr + i*16 + ((lane >> 4) << 2);
    #pragma unroll
    for (int j = 0; j < 4; ++j){
      int col = n0 + wc + j*16 + (lane & 15);
      float bv = ADD_BIAS ? bias[col] : 0.f;
      #pragma unroll
      for (int r = 0; r < 4; ++r){
        float v = acc[i][j][r] + bv;
        if (OUT_BF16) ((u16*)Cout)[(size_t)(rbase + r) * Ndim + col] = f2b(v);
        else          ((float*)Cout)[(size_t)(rbase + r) * Ndim + col] = v;
      }
    }
  }
}

// ---------------- V transpose: vt[bh][d][t] from qkv ----------------
__global__ void k_vt(const u16* __restrict__ qkv, u16* __restrict__ vt){
  __shared__ u16 tl[64][50];
  int t0 = blockIdx.x * 64;
  int bh = blockIdx.y; int b = bh >> 4, h = bh & 15;
  int tid = threadIdx.x;
  for (int i = tid; i < 64*48; i += 256){
    int tt = i / 48, d = i % 48;
    tl[tt][d] = qkv[(size_t)(b*T_ + t0 + tt) * N3_ + 2*C_ + h*D_ + d];
  }
  __syncthreads();
  for (int i = tid; i < 48*64; i += 256){
    int d = i >> 6, tt = i & 63;
    vt[(size_t)(bh*D_ + d) * T_ + t0 + tt] = tl[tt][d];
  }
}

// ---------------- causal flash attention, 128-key tiles ----------------
// grid: 1024 blocks (XCD-swizzled); block = 256 (4 waves). Block owns q-tiles
// (qbA, 31-qbA). Swapped-operand MFMA (S^T = K*Q^T, O^T = V^T*P^T), register-P.
// Each barrier interval stages/computes TWO 64-key strips (128 keys) to halve
// per-iteration overhead (barrier drain + stage issue + loop).
__launch_bounds__(256)
__global__ void k_attn(const u16* __restrict__ qkv, const u16* __restrict__ vt,
                       u16* __restrict__ ao){
  __shared__ u16 lK[2][2][64*64];   // [buf][strip]: 64 key-rows x 128B
  __shared__ u16 lV[2][2][48*64];   // [buf][strip]: 48 d-rows x 128B (sigma-permuted)

  const int wg = ((blockIdx.x & 7) << 7) + (blockIdx.x >> 3);   // 8 XCDs x 128
  const int pairI = wg & 15, bh = wg >> 4;
  const int qbA = pairI, qbB = 31 - pairI;
  const int b = bh >> 4, h = bh & 15;
  const int tid = threadIdx.x, lane = tid & 63, w = tid >> 6;
  const int ls = lane & 15, hi = lane >> 4;
  const f32x4 fzero = {0.f, 0.f, 0.f, 0.f};
  const bf16x8 bzero = {0, 0, 0, 0, 0, 0, 0, 0};

  // ---- Q fragments (B-operand layout; Q pre-scaled via W_attn fold) ----
  bf16x8 aqA[2], aqB[2];
  {
    const u16* qpA = qkv + (size_t)(b*T_ + qbA*64 + w*16 + ls) * N3_ + h*D_ + hi*8;
    aqA[0] = *(const bf16x8*)qpA;
    aqA[1] = (hi < 2) ? *(const bf16x8*)(qpA + 32) : bzero;
    const u16* qpB = qkv + (size_t)(b*T_ + qbB*64 + w*16 + ls) * N3_ + h*D_ + hi*8;
    aqB[0] = *(const bf16x8*)qpB;
    aqB[1] = (hi < 2) ? *(const bf16x8*)(qpB + 32) : bzero;
  }

  // ---- staging addresses ----
  const char* kg0; const char* kg1; const char* vg;
  {
    int c0 = tid,        r0 = c0 >> 3, cb0 = ((c0 & 7) << 4) ^ ((r0 & 7) << 4);
    int c1 = tid + 256,  r1 = c1 >> 3, cb1 = ((c1 & 7) << 4) ^ ((r1 & 7) << 4);
    kg0 = (const char*)(qkv + (size_t)(b*T_ + r0) * N3_ + C_ + h*D_) + cb0;
    kg1 = (const char*)(qkv + (size_t)(b*T_ + r1) * N3_ + C_ + h*D_) + cb1;
    // V: width-4 chunks; logical col k from unswizzle; source key = sigma(k).
    int d0  = tid >> 5;                 // 0..7
    int pb4 = (tid << 2) & 127;         // physical byte in 128B row
    int lb  = pb4 ^ (d0 << 4);          // logical byte
    int k   = lb >> 1;                  // even logical column
    int sk  = (k & 0x23) | ((k & 4) << 2) | ((k & 0x18) >> 1);  // sigma(k)
    vg = (const char*)(vt + (size_t)(bh*D_ + d0) * T_) + (sk << 1);
  }
  const size_t kstep = (size_t)64 * N3_ * 2;   // 64 K-rows per strip

  // stage ONE 64-key strip s into [buf][sl]
  auto STAGE1 = [&](int s, int buf, int sl){
    const size_t ko = (size_t)s * kstep;
    const int vo = s * 128;
    char* kd = (char*)lK[buf][sl];
    char* vd = (char*)lV[buf][sl];
    __builtin_amdgcn_global_load_lds((gptr_t)(kg0 + ko), (lptr_t)(kd + (tid << 4)), 16, 0, 0);
    __builtin_amdgcn_global_load_lds((gptr_t)(kg1 + ko), (lptr_t)(kd + ((tid + 256) << 4)), 16, 0, 0);
    #pragma unroll
    for (int it = 0; it < 6; ++it)
      __builtin_amdgcn_global_load_lds((gptr_t)(vg + vo + it * (8 * T_ * 2)),
          (lptr_t)(vd + ((tid + it*256) << 2)), 4, 0, 0);
  };

  float mrunA = -1e30f, lsumA = 0.f, mrunB = -1e30f, lsumB = 0.f;
  f32x4 oaccA[3], oaccB[3];
  #pragma unroll
  for (int nf = 0; nf < 3; ++nf){ oaccA[nf] = fzero; oaccB[nf] = fzero; }

  int cur = 0;

  // softmax on S^T regs: s[nf][r] = S[key=16nf+4hi+r][q=ls]. Emits P frags.
  auto softmax = [&](f32x4 (&s)[4], float &mrun, float &lsum, f32x4 (&oacc)[3],
                     bf16x8 &pb0, bf16x8 &pb1, bool diag, int krow0, int qt){
    if (diag){
      int qg = qt + w*16 + ls;
      #pragma unroll
      for (int nf = 0; nf < 4; ++nf)
        #pragma unroll
        for (int r = 0; r < 4; ++r){
          int kg = krow0 + nf*16 + hi*4 + r;
          s[nf][r] = (kg <= qg) ? s[nf][r] : -1e30f;
        }
    }
    float m0 = fmaxf(fmaxf(s[0][0], s[0][1]), fmaxf(s[0][2], s[0][3]));
    float m1 = fmaxf(fmaxf(s[1][0], s[1][1]), fmaxf(s[1][2], s[1][3]));
    float m2 = fmaxf(fmaxf(s[2][0], s[2][1]), fmaxf(s[2][2], s[2][3]));
    float m3 = fmaxf(fmaxf(s[3][0], s[3][1]), fmaxf(s[3][2], s[3][3]));
    float mx = fmaxf(fmaxf(m0, m1), fmaxf(m2, m3));
    mx = fmaxf(mx, __shfl_xor(mx, 16));
    mx = fmaxf(mx, __shfl_xor(mx, 32));
    if (__any(mx > mrun)){
      float mn = fmaxf(mrun, mx);
      float corr = __builtin_amdgcn_exp2f(mrun - mn);
      mrun = mn;
      lsum *= corr;
      #pragma unroll
      for (int nf = 0; nf < 3; ++nf)
        #pragma unroll
        for (int r = 0; r < 4; ++r)
          oacc[nf][r] *= corr;
    }
    float p[4][4];
    #pragma unroll
    for (int nf = 0; nf < 4; ++nf)
      #pragma unroll
      for (int r = 0; r < 4; ++r){
        float e = __builtin_amdgcn_exp2f(s[nf][r] - mrun);
        p[nf][r] = e;
        lsum += e;
      }
    union { u32x4 u; bf16x8 b; } w0, w1;
    w0.u.x = cvtpk(p[0][0], p[0][1]); w0.u.y = cvtpk(p[0][2], p[0][3]);
    w0.u.z = cvtpk(p[1][0], p[1][1]); w0.u.w = cvtpk(p[1][2], p[1][3]);
    w1.u.x = cvtpk(p[2][0], p[2][1]); w1.u.y = cvtpk(p[2][2], p[2][3]);
    w1.u.z = cvtpk(p[3][0], p[3][1]); w1.u.w = cvtpk(p[3][2], p[3][3]);
    pb0 = w0.b; pb1 = w1.b;
  };

  // process one 64-key strip (global strip index ks, LDS slot sl)
  auto process = [&](int ks, int sl){
    const bool actA = (ks <= qbA);
    const u16* Kb = lK[cur][sl];
    const u16* Vb = lV[cur][sl];

    f32x4 stA[4], stB[4];
    #pragma unroll
    for (int nf = 0; nf < 4; ++nf){ stA[nf] = fzero; stB[nf] = fzero; }
    #pragma unroll
    for (int kk = 0; kk < 2; ++kk){
      int kbyte = (kk << 6) + (hi << 4);
      #pragma unroll
      for (int nf = 0; nf < 4; ++nf){
        bf16x8 bk = ld_frag(Kb, nf*16 + ls, kbyte);
        stB[nf] = __builtin_amdgcn_mfma_f32_16x16x32_bf16(bk, aqB[kk], stB[nf], 0, 0, 0);
        if (actA)
          stA[nf] = __builtin_amdgcn_mfma_f32_16x16x32_bf16(bk, aqA[kk], stA[nf], 0, 0, 0);
      }
    }

    bf16x8 pbA0, pbA1, pbB0, pbB1;
    if (actA) softmax(stA, mrunA, lsumA, oaccA, pbA0, pbA1, ks == qbA, ks*64, qbA*64);
    softmax(stB, mrunB, lsumB, oaccB, pbB0, pbB1, ks == qbB, ks*64, qbB*64);

    #pragma unroll
    for (int kk = 0; kk < 2; ++kk){
      int kbyte = (kk << 6) + (hi << 4);
      #pragma unroll
      for (int nf = 0; nf < 3; ++nf){
        bf16x8 bv = ld_frag(Vb, nf*16 + ls, kbyte);
        oaccB[nf] = __builtin_amdgcn_mfma_f32_16x16x32_bf16(
            bv, kk ? pbB1 : pbB0, oaccB[nf], 0, 0, 0);
        if (actA)
          oaccA[nf] = __builtin_amdgcn_mfma_f32_16x16x32_bf16(
              bv, kk ? pbA1 : pbA0, oaccA[nf], 0, 0, 0);
      }
    }
  };

  const int kb2max = qbB >> 1;
  STAGE1(0, 0, 0);
  if (qbB >= 1) STAGE1(1, 0, 1);
  __syncthreads();

  for (int kb2 = 0; kb2 <= kb2max; ++kb2){
    if (kb2 < kb2max){
      STAGE1(2*kb2 + 2, cur ^ 1, 0);
      if (2*kb2 + 3 <= qbB) STAGE1(2*kb2 + 3, cur ^ 1, 1);
    }

    process(2*kb2, 0);
    if (2*kb2 + 1 <= qbB) process(2*kb2 + 1, 1);

    if (kb2 < kb2max){
      __syncthreads();
      cur ^= 1;
    }
  }

  // ---- epilogue: finish lsum across hi-groups, normalize, store O^T ----
  float lA = lsumA; lA += __shfl_xor(lA, 16); lA += __shfl_xor(lA, 32);
  float lB = lsumB; lB += __shfl_xor(lB, 16); lB += __shfl_xor(lB, 32);
  float invA = 1.f / lA, invB = 1.f / lB;
  int tA = qbA*64 + w*16 + ls, tB = qbB*64 + w*16 + ls;
  #pragma unroll
  for (int nf = 0; nf < 3; ++nf){
    u16x4 oA, oB;
    #pragma unroll
    for (int r = 0; r < 4; ++r){
      oA[r] = f2b(oaccA[nf][r] * invA);   // O[q=ls][d = nf*16 + 4hi + r]
      oB[r] = f2b(oaccB[nf][r] * invB);
    }
    int col = h*D_ + nf*16 + hi*4;
    *(u16x4*)(ao + (size_t)(b*T_ + tA) * C_ + col) = oA;
    *(u16x4*)(ao + (size_t)(b*T_ + tB) * C_ + col) = oB;
  }
}

extern "C" void kernel_launch(void* const* d_in, const int* in_sizes, int n_in,
                              void* d_out, int out_size, void* d_ws, size_t ws_size,
                              hipStream_t stream){
  if (n_in < 4) return;
  const float* x      = (const float*)d_in[0];
  const float* W_attn = (const float*)d_in[1];
  const float* W_proj = (const float*)d_in[2];
  const float* b_proj = (const float*)d_in[3];

  char* ws = (char*)d_ws;
  size_t off = 0;
  auto alloc = [&](size_t bytes)->void*{
    void* p = ws + off; off += (bytes + 255) & ~(size_t)255; return p;
  };
  u16* xb   = (u16*)alloc((size_t)M_ * C_  * 2);
  u16* wabT = (u16*)alloc((size_t)N3_ * C_ * 2);
  u16* wpbT = (u16*)alloc((size_t)C_ * C_  * 2);
  u16* qkv  = (u16*)alloc((size_t)M_ * N3_ * 2);
  u16* vt   = (u16*)alloc((size_t)B_ * H_ * D_ * T_ * 2);
  u16* ao   = (u16*)alloc((size_t)M_ * C_  * 2);
  if (off > ws_size) return;  // workspace too small — bail cleanly

  const float scale2 = 0.20823527f;    // 48^-0.5 * log2(e), folded into W_attn Q-cols

  k_cvt<<<dim3((M_*C_/4 + 255)/256), dim3(256), 0, stream>>>(x, xb, M_*C_/4);
  k_tpose<<<dim3(N3_/32, C_/32), dim3(256), 0, stream>>>(W_attn, wabT, C_, N3_, C_, scale2);
  k_tpose<<<dim3(C_/32,  C_/32), dim3(256), 0, stream>>>(W_proj, wpbT, C_, C_, 0, 1.f);
  k_gemm<true,false><<<dim3(M_/128, N3_/128), dim3(256), 0, stream>>>(
      xb, wabT, (void*)qkv, (const float*)nullptr, N3_, C_);
  k_vt<<<dim3(T_/64, B_*H_), dim3(256), 0, stream>>>(qkv, vt);
  k_attn<<<dim3(1024), dim3(256), 0, stream>>>(qkv, vt, ao);
  k_gemm<false,true><<<dim3(M_/128, C_/128), dim3(256), 0, stream>>>(
      ao, wpbT, d_out, b_proj, C_, C_);
}